// Round 1
// baseline (11.372 us; speedup 1.0000x reference)
//
#include <hip/hip_runtime.h>

// loss = mean_i( log_qz_cond_x[i] - log_pz[i] )
//      = (1/B) * sum_{i,d} [ -log(scale) + 0.5*z^2 - 0.5*((z-loc)/scale)^2 ]
// (MI_W=TC_W=KL_W=1 makes the decomposed terms telescope; log_qz and
//  log_qz_prod cancel exactly, so the B*B*D pairwise matrix is never needed.)

#define BATCH 2048
#define NDIM 64
#define NELEM (BATCH * NDIM)        // 131072
#define NVEC (NELEM / 4)            // 32768 float4 per input
#define BLOCKS 128
#define THREADS 256                 // BLOCKS*THREADS == NVEC exactly

__device__ __forceinline__ float term(float z, float mu, float sg) {
    float t = (z - mu) / sg;
    return 0.5f * z * z - 0.5f * t * t - logf(sg);
}

__global__ __launch_bounds__(THREADS) void kld_partial_kernel(
    const float* __restrict__ z, const float* __restrict__ loc,
    const float* __restrict__ scale, double* __restrict__ ws) {
    int idx = blockIdx.x * THREADS + threadIdx.x;   // 0 .. NVEC-1
    float4 zv = reinterpret_cast<const float4*>(z)[idx];
    float4 lv = reinterpret_cast<const float4*>(loc)[idx];
    float4 sv = reinterpret_cast<const float4*>(scale)[idx];

    float acc = term(zv.x, lv.x, sv.x)
              + term(zv.y, lv.y, sv.y)
              + term(zv.z, lv.z, sv.z)
              + term(zv.w, lv.w, sv.w);

    double d = (double)acc;
    // wave64 butterfly-free down-reduce
    #pragma unroll
    for (int off = 32; off > 0; off >>= 1)
        d += __shfl_down(d, off, 64);

    __shared__ double sm[THREADS / 64];
    int lane = threadIdx.x & 63;
    int wid = threadIdx.x >> 6;
    if (lane == 0) sm[wid] = d;
    __syncthreads();
    if (threadIdx.x == 0) {
        double s = 0.0;
        #pragma unroll
        for (int w = 0; w < THREADS / 64; ++w) s += sm[w];
        ws[blockIdx.x] = s;
    }
}

__global__ __launch_bounds__(BLOCKS) void kld_final_kernel(
    const double* __restrict__ ws, float* __restrict__ out) {
    double d = ws[threadIdx.x];     // BLOCKS == 128 threads, one partial each
    #pragma unroll
    for (int off = 32; off > 0; off >>= 1)
        d += __shfl_down(d, off, 64);

    __shared__ double sm[2];
    if ((threadIdx.x & 63) == 0) sm[threadIdx.x >> 6] = d;
    __syncthreads();
    if (threadIdx.x == 0)
        out[0] = (float)((sm[0] + sm[1]) / (double)BATCH);
}

extern "C" void kernel_launch(void* const* d_in, const int* in_sizes, int n_in,
                              void* d_out, int out_size, void* d_ws, size_t ws_size,
                              hipStream_t stream) {
    const float* z     = (const float*)d_in[0];
    const float* loc   = (const float*)d_in[1];
    const float* scale = (const float*)d_in[2];
    float* out = (float*)d_out;
    double* ws = (double*)d_ws;

    kld_partial_kernel<<<BLOCKS, THREADS, 0, stream>>>(z, loc, scale, ws);
    kld_final_kernel<<<1, BLOCKS, 0, stream>>>(ws, out);
}

// Round 2
// 10.743 us; speedup vs baseline: 1.0585x; 1.0585x over previous
//
#include <hip/hip_runtime.h>

// loss = mean_i( log_qz_cond_x[i] - log_pz[i] )
//      = (1/B) * sum_{i,d} [ -log(scale) + 0.5*z^2 - 0.5*((z-loc)/scale)^2 ]
// (MI_W=TC_W=KL_W=1 telescopes the decomposition; log_qz and log_qz_prod
//  cancel exactly, so the B*B*D pairwise matrix is never needed.)
//
// Single-launch fused reduction: 128 blocks write double partials to d_ws,
// bump a device-scope counter; the 128th arrival re-reduces in fixed order
// and writes out. Counter test is (old % 128 == 127) so it works for ANY
// initial (poisoned) counter value and needs no reset between replays.

#define BATCH 2048
#define NELEM (BATCH * 64)          // 131072
#define NVEC (NELEM / 4)            // 32768 float4 per input
#define BLOCKS 128
#define THREADS 256                 // BLOCKS*THREADS == NVEC exactly

__device__ __forceinline__ float term(float z, float mu, float sg) {
    float t = (z - mu) / sg;
    return 0.5f * z * z - 0.5f * t * t - logf(sg);
}

__global__ __launch_bounds__(THREADS) void kld_fused_kernel(
    const float* __restrict__ z, const float* __restrict__ loc,
    const float* __restrict__ scale, float* __restrict__ out,
    double* __restrict__ partials, unsigned int* __restrict__ counter) {
    int idx = blockIdx.x * THREADS + threadIdx.x;   // 0 .. NVEC-1
    float4 zv = reinterpret_cast<const float4*>(z)[idx];
    float4 lv = reinterpret_cast<const float4*>(loc)[idx];
    float4 sv = reinterpret_cast<const float4*>(scale)[idx];

    float acc = term(zv.x, lv.x, sv.x)
              + term(zv.y, lv.y, sv.y)
              + term(zv.z, lv.z, sv.z)
              + term(zv.w, lv.w, sv.w);

    double d = (double)acc;
    #pragma unroll
    for (int off = 32; off > 0; off >>= 1)
        d += __shfl_down(d, off, 64);

    __shared__ double sm[THREADS / 64];
    __shared__ int s_last;
    int lane = threadIdx.x & 63;
    int wid  = threadIdx.x >> 6;
    if (lane == 0) sm[wid] = d;
    __syncthreads();

    if (threadIdx.x == 0) {
        double s = 0.0;
        #pragma unroll
        for (int w = 0; w < THREADS / 64; ++w) s += sm[w];
        // publish partial (device scope), then arrive at the counter
        __hip_atomic_store(&partials[blockIdx.x], s, __ATOMIC_RELEASE,
                           __HIP_MEMORY_SCOPE_AGENT);
        unsigned int old = __hip_atomic_fetch_add(counter, 1u, __ATOMIC_ACQ_REL,
                                                  __HIP_MEMORY_SCOPE_AGENT);
        s_last = ((old & (BLOCKS - 1u)) == (BLOCKS - 1u));
    }
    __syncthreads();

    if (s_last) {
        // this block saw all 128 arrivals; re-reduce partials in FIXED order
        double v = 0.0;
        if (threadIdx.x < BLOCKS)
            v = __hip_atomic_load(&partials[threadIdx.x], __ATOMIC_ACQUIRE,
                                  __HIP_MEMORY_SCOPE_AGENT);
        #pragma unroll
        for (int off = 32; off > 0; off >>= 1)
            v += __shfl_down(v, off, 64);
        if (lane == 0) sm[wid] = v;
        __syncthreads();
        if (threadIdx.x == 0) {
            double t = 0.0;
            #pragma unroll
            for (int w = 0; w < THREADS / 64; ++w) t += sm[w];
            out[0] = (float)(t / (double)BATCH);
        }
    }
}

extern "C" void kernel_launch(void* const* d_in, const int* in_sizes, int n_in,
                              void* d_out, int out_size, void* d_ws, size_t ws_size,
                              hipStream_t stream) {
    const float* z     = (const float*)d_in[0];
    const float* loc   = (const float*)d_in[1];
    const float* scale = (const float*)d_in[2];
    float* out = (float*)d_out;
    double* partials   = (double*)d_ws;
    unsigned int* counter = (unsigned int*)((char*)d_ws + BLOCKS * sizeof(double));

    kld_fused_kernel<<<BLOCKS, THREADS, 0, stream>>>(z, loc, scale, out,
                                                     partials, counter);
}